// Round 5
// baseline (3927.375 us; speedup 1.0000x reference)
//
#include <hip/hip_runtime.h>

#define TSEQ 2048
#define DM   1024
#define NBLK 4
#define NHEAD 16
#define HDIM 64
#define DFF  4096
#define NVOC 32000

typedef unsigned short u16;
typedef __attribute__((ext_vector_type(8))) short short8;
typedef __attribute__((ext_vector_type(4))) float f32x4;

// ---------------- device-global scratch ----------------
// f32 residual stream
__device__ float g_h[TSEQ * DM];
// K-packed bf16x3 activations: A' = [hi | lo | hi] along K
__device__ u16 g_xnp[TSEQ * 3 * DM];
__device__ u16 g_ffp[TSEQ * 3 * DFF];
// attention operands, bf16 hi/lo; Q,K row-major [T][D]; V transposed [D][T]
__device__ u16 g_qh[TSEQ * DM], g_ql[TSEQ * DM];
__device__ u16 g_kh[TSEQ * DM], g_kl[TSEQ * DM];
__device__ u16 g_vth[DM * TSEQ], g_vtl[DM * TSEQ];
// K-packed bf16x3 transposed weights [N][3K]: B' = [hi | hi | lo] along K
__device__ u16 g_wqkvp[NBLK * 3 * DM * 3 * DM];
__device__ u16 g_w1p[NBLK * DFF * 3 * DM];
__device__ u16 g_w2p[NBLK * DM * 3 * DFF];
__device__ u16 g_wvp[NVOC * 3 * DM];
__device__ float g_bqkv[NBLK * 3 * DM];

// ---------------- helpers ----------------
__device__ __forceinline__ u16 f2bf(float x) {           // RNE f32 -> bf16
  union { float f; unsigned u; } v; v.f = x;
  unsigned r = (v.u >> 16) & 1u;
  return (u16)((v.u + 0x7fffu + r) >> 16);
}
__device__ __forceinline__ float b2f(u16 h) {
  union { float f; unsigned u; } v; v.u = ((unsigned)h) << 16; return v.f;
}
// async global->LDS, 16B per lane; LDS dest = wave-uniform base + lane*16
__device__ __forceinline__ void load16(const u16* g, u16* l) {
  __builtin_amdgcn_global_load_lds(
      (const __attribute__((address_space(1))) unsigned int*)(const void*)g,
      (__attribute__((address_space(3))) unsigned int*)(void*)l, 16, 0, 0);
}

__device__ __forceinline__ u16* wsel_p(int s) {
  switch (s) { case 0: return g_wqkvp; case 1: return g_w1p;
               case 2: return g_w2p;   default: return g_wvp; }
}

template <int N> __device__ __forceinline__ void waitvm() {
  if constexpr (N == 8)      asm volatile("s_waitcnt vmcnt(8)" ::: "memory");
  else if constexpr (N == 4) asm volatile("s_waitcnt vmcnt(4)" ::: "memory");
  else if constexpr (N == 3) asm volatile("s_waitcnt vmcnt(3)" ::: "memory");
  else                       asm volatile("s_waitcnt vmcnt(0)" ::: "memory");
}

// ---------------- embedding ----------------
__global__ __launch_bounds__(256) void embed_kernel(const int* __restrict__ x,
                                                    const float* __restrict__ tok,
                                                    const float* __restrict__ pos) {
  int t = blockIdx.x;
  const float* trow = tok + (long)x[t] * DM;
  const float* prow = pos + (long)t * DM;
  float* hrow = g_h + (long)t * DM;
  for (int i = threadIdx.x; i < DM; i += 256)
    hrow[i] = trow[i] + prow[i];
}

// ------------- layernorm: g_h -> g_xnp packed [hi|lo|hi] -------------
__global__ __launch_bounds__(256) void ln_kernel(const float* __restrict__ gamma,
                                                 const float* __restrict__ beta) {
  int t = blockIdx.x;
  const float* xr = g_h + (long)t * DM;
  float s = 0.f, ss = 0.f;
  for (int i = threadIdx.x; i < DM; i += 256) {
    float v = xr[i];
    s += v; ss += v * v;
  }
#pragma unroll
  for (int off = 32; off; off >>= 1) {
    s  += __shfl_down(s, off);
    ss += __shfl_down(ss, off);
  }
  __shared__ float red[2][4];
  int w = threadIdx.x >> 6;
  if ((threadIdx.x & 63) == 0) { red[0][w] = s; red[1][w] = ss; }
  __syncthreads();
  s  = red[0][0] + red[0][1] + red[0][2] + red[0][3];
  ss = red[1][0] + red[1][1] + red[1][2] + red[1][3];
  float mean = s * (1.f / DM);
  float var  = ss * (1.f / DM) - mean * mean;
  float rstd = rsqrtf(var + 1e-5f);
  u16* orow = g_xnp + (long)t * 3 * DM;
  for (int i = threadIdx.x; i < DM; i += 256) {
    float xv = (xr[i] - mean) * rstd * gamma[i] + beta[i];
    u16 h = f2bf(xv);
    u16 lo = f2bf(xv - b2f(h));
    orow[i] = h;
    orow[DM + i] = lo;
    orow[2 * DM + i] = h;
  }
}

// ------------- weight transpose + K-packed bf16x3 split -------------
// src element (k,n) at src[(n>>6)*sH + k*sD + (n&63)]
// dst [N][3K]: [k]=hi, [K+k]=hi, [2K+k]=lo.  grid = (N/64, K/64)
__global__ __launch_bounds__(256) void wpack_t(const float* __restrict__ src,
                                               int dsel, long doff,
                                               int K, long sD, long sH) {
  __shared__ float tile[64][65];
  u16* dp = wsel_p(dsel) + doff;
  int n0 = blockIdx.x * 64, k0 = blockIdx.y * 64;
  int tid = threadIdx.x, ln = tid & 63, sub = tid >> 6;
  const float* sbase = src + (long)(n0 >> 6) * sH + ln;
#pragma unroll
  for (int r = 0; r < 16; ++r) {
    int kk = sub * 16 + r;
    tile[kk][ln] = sbase[(long)(k0 + kk) * sD];
  }
  __syncthreads();
#pragma unroll
  for (int r = 0; r < 16; ++r) {
    int nn = sub * 16 + r;
    float v = tile[ln][nn];               // element (k0+ln, n0+nn)
    long o = (long)(n0 + nn) * 3 * K + k0 + ln;
    u16 h = f2bf(v);
    u16 lo = f2bf(v - b2f(h));
    dp[o] = h;
    dp[o + K] = h;
    dp[o + 2 * K] = lo;
  }
}

// concat q/k/v biases per layer into g_bqkv[NBLK][3*DM]
__global__ __launch_bounds__(256) void bias_qkv(const float* __restrict__ bq,
                                                const float* __restrict__ bk,
                                                const float* __restrict__ bv) {
  int i = blockIdx.x * 256 + threadIdx.x;
  int l = i / (3 * DM);
  int j = i % (3 * DM);
  const float* s = (j < DM) ? bq : (j < 2 * DM) ? bk : bv;
  g_bqkv[i] = s[(long)l * DM + (j & (DM - 1))];
}

// ------------- MFMA GEMM: plain bf16 over K-packed x3 operands -------------
// Counted-vmcnt depth-2 pipeline: raw s_barrier, vmcnt never drained to 0 in
// steady state.  Grid: x = m-block (B-panel reuse), y = n-block.
// LDS chunk = one 16-row x 32-K fragment tile (1KB), frag-ordered for both
// global_load_lds dest (lane*16B) and ds_read_b128 (row=lane&15, k=(lane>>4)*8).
// outmode: 0 = f32 -> Cout; 1 = packed [hi|lo|hi] -> g_ffp;
//          2 = qkv: q,k -> hi/lo [T][D]; v -> hi/lo transposed [D][T]
//          3 = residual add -> g_h (f32)
template <int BM, int BN, int BK, int WM, int WN>
__global__ __launch_bounds__(WM * WN * 64, 2) void gemm_mfma(
    int aSel, int wSel, long woff,
    const float* __restrict__ biasPtr, long boff, float* __restrict__ Cout,
    int N, int K, int relu, int outmode) {
  constexpr int WAVES = WM * WN;
  constexpr int KS = BK / 32;               // 16x16x32 k-steps per K-tile
  constexpr int MI = BM / (16 * WM);        // m-frags per wave
  constexpr int NI = BN / (16 * WN);        // n-frags per wave
  constexpr int CA = (BM / 16) * KS;        // A 1KB-chunks per K-tile
  constexpr int CB = (BN / 16) * KS;
  constexpr int L  = (CA + CB) / WAVES;     // global_load_lds per wave per STAGE
  __shared__ __align__(16) u16 lA[2][CA * 512];
  __shared__ __align__(16) u16 lB[2][CB * 512];

  const u16* Ap = aSel ? g_ffp : g_xnp;
  const u16* Bp = wsel_p(wSel) + woff;
  const float* bias = biasPtr ? biasPtr : (g_bqkv + boff);

  const int tid = threadIdx.x;
  const int w = tid >> 6, lane = tid & 63;
  const int wr = w / WN, wc = w % WN;
  const int m0 = blockIdx.x * BM;
  const int n0 = blockIdx.y * BN;
  const int grp = lane >> 4, l16 = lane & 15;

  auto STAGE = [&](int kk, int d) {
#pragma unroll
    for (int i = 0; i < L; ++i) {
      const int c = w * L + i;              // wave-uniform chunk id
      if (c < CA) {
        const int ks = c / (BM / 16), f = c % (BM / 16);
        load16(Ap + (long)(m0 + f * 16 + (lane >> 2)) * K + kk + ks * 32 + (lane & 3) * 8,
               &lA[d][c * 512]);
      } else {
        const int cb = c - CA;
        const int ks = cb / (BN / 16), f = cb % (BN / 16);
        load16(Bp + (long)(n0 + f * 16 + (lane >> 2)) * K + kk + ks * 32 + (lane & 3) * 8,
               &lB[d][cb * 512]);
      }
    }
  };

  f32x4 acc[MI][NI] = {};

  STAGE(0, 0);                  // vm: L
  STAGE(BK, 1);                 // vm: 2L
  waitvm<L>();                  // tile 0 resident
  __builtin_amdgcn_sched_barrier(0);
  __builtin_amdgcn_s_barrier();

  int cur = 0;
  for (int k0 = 0; k0 < K; k0 += BK) {
#pragma unroll
    for (int ks = 0; ks < KS; ++ks) {
      short8 a[MI], b[NI];
#pragma unroll
      for (int mi = 0; mi < MI; ++mi)
        a[mi] = *(const short8*)(const void*)
            &lA[cur][(ks * (BM / 16) + wr * MI + mi) * 512 + l16 * 32 + grp * 8];
#pragma unroll
      for (int ni = 0; ni < NI; ++ni)
        b[ni] = *(const short8*)(const void*)
            &lB[cur][(ks * (BN / 16) + wc * NI + ni) * 512 + l16 * 32 + grp * 8];
#pragma unroll
      for (int mi = 0; mi < MI; ++mi)
#pragma unroll
        for (int ni = 0; ni < NI; ++ni)
          acc[mi][ni] = __builtin_amdgcn_mfma_f32_16x16x32_bf16(a[mi], b[ni], acc[mi][ni], 0, 0, 0);
    }
    // all my ds_reads of buf[cur] complete before anyone overwrites it
    asm volatile("s_waitcnt lgkmcnt(0)" ::: "memory");
    __builtin_amdgcn_sched_barrier(0);
    __builtin_amdgcn_s_barrier();
    if (k0 + 2 * BK < K) {
      STAGE(k0 + 2 * BK, cur);  // depth-2 prefetch into just-freed buffer
      waitvm<L>();              // oldest L = next tile's loads -> resident
    } else {
      waitvm<0>();              // tail: drain remaining
    }
    __builtin_amdgcn_sched_barrier(0);
    __builtin_amdgcn_s_barrier();
    cur ^= 1;
  }

  // epilogue: C/D layout col = lane&15, row = (lane>>4)*4 + r
#pragma unroll
  for (int mi = 0; mi < MI; ++mi)
#pragma unroll
    for (int ni = 0; ni < NI; ++ni) {
      const int col = n0 + wc * (NI * 16) + ni * 16 + l16;
      const int row0 = m0 + wr * (MI * 16) + mi * 16 + (grp << 2);
      const float bv = bias[col];
#pragma unroll
      for (int r = 0; r < 4; ++r) {
        float v2 = acc[mi][ni][r] + bv;
        if (relu) v2 = fmaxf(v2, 0.f);
        const long row = row0 + r;
        if (outmode == 0) {
          Cout[row * (long)N + col] = v2;
        } else if (outmode == 1) {
          long oo = row * (long)(3 * N) + col;
          u16 hh = f2bf(v2);
          u16 ll = f2bf(v2 - b2f(hh));
          g_ffp[oo] = hh;
          g_ffp[oo + N] = ll;
          g_ffp[oo + 2 * N] = hh;
        } else if (outmode == 2) {
          u16 hh = f2bf(v2), ll = f2bf(v2 - b2f(hh));
          if (col < DM) {
            long oo = row * (long)DM + col;
            g_qh[oo] = hh; g_ql[oo] = ll;
          } else if (col < 2 * DM) {
            long oo = row * (long)DM + (col - DM);
            g_kh[oo] = hh; g_kl[oo] = ll;
          } else {
            long oo = (long)(col - 2 * DM) * TSEQ + row;   // V^T [D][T]
            g_vth[oo] = hh; g_vtl[oo] = ll;
          }
        } else {
          long oo = row * (long)N + col;
          g_h[oo] += v2;
        }
      }
    }
}

// ---------------- flash attention, MFMA bf16x3, online softmax (unchanged) --
__global__ __launch_bounds__(256) void attn_kernel() {
  __shared__ __align__(16) u16 kbuf[2][4][2][512];   // [hl][s-tile][kstep][lane*8]
  __shared__ __align__(16) u16 vbuf[2][4][2][512];   // [hl][d-tile][kstep][lane*8]
  __shared__ __align__(16) u16 Ph[64][72];
  __shared__ __align__(16) u16 Pl[64][72];
  const int hd = blockIdx.y;
  const int q0 = blockIdx.x * 64;
  const int tid = threadIdx.x;
  const int w = tid >> 6, lane = tid & 63;
  const int grp = lane >> 4, l16 = lane & 15;
  const float scale = 0.03125f;   // 1/sqrt(DM) = 1/32 (reference scales by D!)

  short8 qf[2][2];
#pragma unroll
  for (int hl = 0; hl < 2; ++hl)
#pragma unroll
    for (int ks = 0; ks < 2; ++ks) {
      const u16* src = (hl ? g_ql : g_qh)
          + (long)(q0 + w * 16 + l16) * DM + hd * HDIM + ks * 32 + grp * 8;
      qf[hl][ks] = *(const short8*)(const void*)src;
    }

  float mrun[4] = {-1e30f, -1e30f, -1e30f, -1e30f};
  float lrun[4] = {0.f, 0.f, 0.f, 0.f};
  f32x4 o[4] = {};

  for (int s0 = 0; s0 <= q0; s0 += 64) {
    __syncthreads();                       // prev-iter LDS reads done
#pragma unroll
    for (int i = 0; i < 8; ++i) {
      int rid = w * 8 + i;
      int r = rid & 15;
      int hl = r >> 3, nt = (r >> 1) & 3, ks = r & 1;
      if (rid < 16) {
        const u16* src = (hl ? g_kl : g_kh)
            + (long)(s0 + nt * 16 + l16) * DM + hd * HDIM + ks * 32 + grp * 8;
        load16(src, &kbuf[hl][nt][ks][0]);
      } else {
        const u16* src = (hl ? g_vtl : g_vth)
            + (long)(hd * HDIM + nt * 16 + l16) * TSEQ + s0 + ks * 32 + grp * 8;
        load16(src, &vbuf[hl][nt][ks][0]);
      }
    }
    __syncthreads();                       // staging visible (vmcnt drained)

    // S = Q K^T  (bf16x3: hh + hl + lh)
    f32x4 sa[4] = {};
#pragma unroll
    for (int nt = 0; nt < 4; ++nt)
#pragma unroll
      for (int ks = 0; ks < 2; ++ks) {
        short8 kh = *(const short8*)(const void*)&kbuf[0][nt][ks][lane * 8];
        short8 kl = *(const short8*)(const void*)&kbuf[1][nt][ks][lane * 8];
        sa[nt] = __builtin_amdgcn_mfma_f32_16x16x32_bf16(qf[0][ks], kh, sa[nt], 0, 0, 0);
        sa[nt] = __builtin_amdgcn_mfma_f32_16x16x32_bf16(qf[0][ks], kl, sa[nt], 0, 0, 0);
        sa[nt] = __builtin_amdgcn_mfma_f32_16x16x32_bf16(qf[1][ks], kh, sa[nt], 0, 0, 0);
      }

    float p[4][4];
#pragma unroll
    for (int nt = 0; nt < 4; ++nt)
#pragma unroll
      for (int r = 0; r < 4; ++r) {
        float sc = sa[nt][r] * scale;
        int s = s0 + nt * 16 + l16;
        int q = q0 + w * 16 + grp * 4 + r;
        p[nt][r] = (s > q) ? -1e30f : sc;
      }

#pragma unroll
    for (int r = 0; r < 4; ++r) {
      float rm = fmaxf(fmaxf(p[0][r], p[1][r]), fmaxf(p[2][r], p[3][r]));
#pragma unroll
      for (int off = 8; off; off >>= 1) rm = fmaxf(rm, __shfl_xor(rm, off));
      float mn = fmaxf(mrun[r], rm);
      float al = __expf(mrun[r] - mn);
      mrun[r] = mn;
      float ps = 0.f;
#pragma unroll
      for (int nt = 0; nt < 4; ++nt) { p[nt][r] = __expf(p[nt][r] - mn); ps += p[nt][r]; }
#pragma unroll
      for (int off = 8; off; off >>= 1) ps += __shfl_xor(ps, off);
      lrun[r] = lrun[r] * al + ps;
      o[0][r] *= al; o[1][r] *= al; o[2][r] *= al; o[3][r] *= al;
    }

#pragma unroll
    for (int nt = 0; nt < 4; ++nt)
#pragma unroll
      for (int r = 0; r < 4; ++r) {
        float pv = p[nt][r];
        u16 hh = f2bf(pv);
        Ph[w * 16 + grp * 4 + r][nt * 16 + l16] = hh;
        Pl[w * 16 + grp * 4 + r][nt * 16 + l16] = f2bf(pv - b2f(hh));
      }

#pragma unroll
    for (int ks = 0; ks < 2; ++ks) {
      short8 pah = *(const short8*)(const void*)&Ph[w * 16 + l16][ks * 32 + grp * 8];
      short8 pal = *(const short8*)(const void*)&Pl[w * 16 + l16][ks * 32 + grp * 8];
#pragma unroll
      for (int nt = 0; nt < 4; ++nt) {
        short8 vh = *(const short8*)(const void*)&vbuf[0][nt][ks][lane * 8];
        short8 vl = *(const short8*)(const void*)&vbuf[1][nt][ks][lane * 8];
        o[nt] = __builtin_amdgcn_mfma_f32_16x16x32_bf16(pah, vh, o[nt], 0, 0, 0);
        o[nt] = __builtin_amdgcn_mfma_f32_16x16x32_bf16(pah, vl, o[nt], 0, 0, 0);
        o[nt] = __builtin_amdgcn_mfma_f32_16x16x32_bf16(pal, vh, o[nt], 0, 0, 0);
      }
    }
  }

  float rl[4];
#pragma unroll
  for (int r = 0; r < 4; ++r) rl[r] = 1.f / lrun[r];
#pragma unroll
  for (int nt = 0; nt < 4; ++nt)
#pragma unroll
    for (int r = 0; r < 4; ++r)
      g_h[(long)(q0 + w * 16 + grp * 4 + r) * DM + hd * HDIM + nt * 16 + l16]
          += o[nt][r] * rl[r];
}

extern "C" void kernel_launch(void* const* d_in, const int* in_sizes, int n_in,
                              void* d_out, int out_size, void* d_ws, size_t ws_size,
                              hipStream_t stream) {
  (void)in_sizes; (void)n_in; (void)out_size; (void)d_ws; (void)ws_size;
  const int*   x    = (const int*)  d_in[0];
  const float* tok  = (const float*)d_in[1];
  const float* pos  = (const float*)d_in[2];
  const float* wq   = (const float*)d_in[3];
  const float* bq   = (const float*)d_in[4];
  const float* wk   = (const float*)d_in[5];
  const float* bk   = (const float*)d_in[6];
  const float* wv   = (const float*)d_in[7];
  const float* bv   = (const float*)d_in[8];
  const float* ln1g = (const float*)d_in[9];
  const float* ln1b = (const float*)d_in[10];
  const float* ln2g = (const float*)d_in[11];
  const float* ln2b = (const float*)d_in[12];
  const float* w1   = (const float*)d_in[13];
  const float* b1   = (const float*)d_in[14];
  const float* w2   = (const float*)d_in[15];
  const float* b2   = (const float*)d_in[16];
  const float* lnfg = (const float*)d_in[17];
  const float* lnfb = (const float*)d_in[18];
  const float* wvoc = (const float*)d_in[19];
  const float* bvoc = (const float*)d_in[20];
  float* out = (float*)d_out;

  // ---- weight conversion (transpose + K-packed bf16x3), every launch ----
  for (int l = 0; l < NBLK; ++l) {
    long base = (long)l * (3 * DM) * (3 * DM);
    wpack_t<<<dim3(DM / 64, DM / 64), 256, 0, stream>>>(
        wq + (long)l * DM * DM, 0, base,                          DM, HDIM, (long)DM * HDIM);
    wpack_t<<<dim3(DM / 64, DM / 64), 256, 0, stream>>>(
        wk + (long)l * DM * DM, 0, base + (long)DM * 3 * DM,      DM, HDIM, (long)DM * HDIM);
    wpack_t<<<dim3(DM / 64, DM / 64), 256, 0, stream>>>(
        wv + (long)l * DM * DM, 0, base + 2L * DM * 3 * DM,       DM, HDIM, (long)DM * HDIM);
    wpack_t<<<dim3(DFF / 64, DM / 64), 256, 0, stream>>>(
        w1 + (long)l * DM * DFF, 1, (long)l * DFF * 3 * DM, DM, DFF, 64);
    wpack_t<<<dim3(DM / 64, DFF / 64), 256, 0, stream>>>(
        w2 + (long)l * DFF * DM, 2, (long)l * DM * 3 * DFF, DFF, DM, 64);
  }
  wpack_t<<<dim3(NVOC / 64, DM / 64), 256, 0, stream>>>(wvoc, 3, 0, DM, NVOC, 64);
  bias_qkv<<<NBLK * 3 * DM / 256, 256, 0, stream>>>(bq, bk, bv);

  // ---- forward pass (all GEMMs: grid.x = m-blocks, grid.y = n-blocks) ----
  embed_kernel<<<TSEQ, 256, 0, stream>>>(x, tok, pos);
  for (int l = 0; l < NBLK; ++l) {
    long base = (long)l * (3 * DM) * (3 * DM);
    ln_kernel<<<TSEQ, 256, 0, stream>>>(ln1g + l * DM, ln1b + l * DM);
    // fused QKV: 128x128 tile, 384 blocks
    gemm_mfma<128, 128, 32, 2, 2><<<dim3(TSEQ / 128, 3 * DM / 128), 256, 0, stream>>>(
        0, 0, base, nullptr, (long)l * 3 * DM, nullptr, 3 * DM, 3 * DM, 0, 2);
    attn_kernel<<<dim3(TSEQ / 64, NHEAD), 256, 0, stream>>>();
    ln_kernel<<<TSEQ, 256, 0, stream>>>(ln2g + l * DM, ln2b + l * DM);
    // FF1: relu, packed output; 128x128 tile, 512 blocks
    gemm_mfma<128, 128, 32, 2, 2><<<dim3(TSEQ / 128, DFF / 128), 256, 0, stream>>>(
        0, 1, (long)l * DFF * 3 * DM, b1 + (long)l * DFF, 0, nullptr, DFF, 3 * DM, 1, 1);
    // FF2: residual add; 64x128 tile, 256 blocks
    gemm_mfma<64, 128, 32, 1, 4><<<dim3(TSEQ / 64, DM / 128), 256, 0, stream>>>(
        1, 2, (long)l * DM * 3 * DFF, b2 + (long)l * DM, 0, nullptr, DM, 3 * DFF, 0, 3);
  }
  ln_kernel<<<TSEQ, 256, 0, stream>>>(lnfg, lnfb);
  // vocab: 256x256 tile, BK=64, 8 waves, 1000 blocks
  gemm_mfma<256, 256, 64, 2, 4><<<dim3(TSEQ / 256, NVOC / 256), 512, 0, stream>>>(
      0, 3, 0, bvoc, 0, out, NVOC, 3 * DM, 0, 0);
}